// Round 2
// baseline (540.975 us; speedup 1.0000x reference)
//
#include <hip/hip_runtime.h>
#include <cfloat>
#include <cmath>

#define B_   8
#define N_   8192
#define S_   2048
#define C1_  128
#define C2_  256
#define T_   256
#define CIN_ 384
#define CO_  256

typedef __attribute__((ext_vector_type(8))) short short8;
typedef __attribute__((ext_vector_type(4))) float f32x4;

// ---------- helpers ----------
__device__ __forceinline__ float bf2f(unsigned short u) {
    union { unsigned int i; float f; } v; v.i = ((unsigned int)u) << 16; return v.f;
}
__device__ __forceinline__ unsigned short f2bf(float f) {
    union { float f; unsigned int i; } v; v.f = f;
    unsigned int i = v.i;
    unsigned int r = i + 0x7FFFu + ((i >> 16) & 1u);   // RNE
    return (unsigned short)(r >> 16);
}
__device__ __forceinline__ float gelu_f(float x) {
    return 0.5f * x * (1.0f + erff(x * 0.70710678118654752440f));
}
__device__ __forceinline__ void async16(const void* g, void* l) {
    __builtin_amdgcn_global_load_lds((const __attribute__((address_space(1))) void*)g,
                                     (__attribute__((address_space(3))) void*)l, 16, 0, 0);
}

// ---------- ws layout (bytes) ----------
#define OFF_TE1   0u          // 8*384*4 = 12288
#define OFF_TE2   16384u      // 8*256*4 = 8192
#define OFF_STATS 24576u      // 4 x 256 floats = 4096 (sum1, sq1, sum2, sq2)
#define OFF_BN1   28672u      // scale1(1024) shift1(1024)
#define OFF_BN2   30720u
#define OFF_IDX   32768u      // 65536*3*4 = 786432
#define OFF_WTS   819200u     // 786432
#define OFF_WC1   1605632u    // 98304*2 = 196608 (w_c1 bf16)
#define OFF_WC2   1802240u    // 65536*2 = 131072 (w_c2 bf16)
#define OFF_P2T   2097152u    // 8*2048*256*2 = 8388608 (bf16)
#define OFF_X1    10485760u   // 8*8192*384*2 = 50331648 (bf16; reused as Z after gemm1)
#define OFF_Y     60817408u   // 8*8192*256*2 = 33554432 (bf16)
// total 94371840 bytes (~90 MB)

// ---------- weight fp32 -> bf16 ----------
__global__ __launch_bounds__(256) void wcvt_kernel(
    const float* __restrict__ w1, const float* __restrict__ w2,
    unsigned short* __restrict__ o1, unsigned short* __restrict__ o2)
{
    int g = blockIdx.x * 256 + threadIdx.x;          // grid 384*256 = 98304
    o1[g] = f2bf(w1[g]);
    if (g < CO_ * CO_) o2[g] = f2bf(w2[g]);
}

// ---------- te1/te2 (fp32 in, fp32 out) ----------
__global__ __launch_bounds__(640) void te_kernel(
    const float* __restrict__ t_embed,
    const float* __restrict__ w_t1, const float* __restrict__ b_t1,
    const float* __restrict__ w_t2, const float* __restrict__ b_t2,
    float* __restrict__ te1, float* __restrict__ te2)
{
    __shared__ float gt[T_];
    int b = blockIdx.x, t = threadIdx.x;
    if (t < T_) gt[t] = gelu_f(t_embed[b * T_ + t]);
    __syncthreads();
    if (t < CIN_) {
        const float* w = w_t1 + t * T_;
        float s = 0.f;
        for (int k = 0; k < T_; ++k) s += gt[k] * w[k];
        te1[b * CIN_ + t] = s + b_t1[t];
    } else {
        int o = t - CIN_;
        const float* w = w_t2 + o * T_;
        float s = 0.f;
        for (int k = 0; k < T_; ++k) s += gt[k] * w[k];
        te2[b * CO_ + o] = s + b_t2[o];
    }
}

// ---------- 3-NN (fp32 xyz) ----------
__global__ __launch_bounds__(256) void knn_kernel(
    const float* __restrict__ xyz1, const float* __restrict__ xyz2,
    int* __restrict__ idx, float* __restrict__ wts)
{
    __shared__ float4 sp[S_];   // 32 KB: x,y,z,|p|^2
    int b = blockIdx.y, tid = threadIdx.x;
    for (int s = tid; s < S_; s += 256) {
        float x = xyz2[(b * S_ + s) * 3 + 0];
        float y = xyz2[(b * S_ + s) * 3 + 1];
        float z = xyz2[(b * S_ + s) * 3 + 2];
        sp[s] = make_float4(x, y, z, x * x + y * y + z * z);
    }
    __syncthreads();
    int n = blockIdx.x * 256 + tid;
    float x1 = xyz1[(b * N_ + n) * 3 + 0];
    float y1 = xyz1[(b * N_ + n) * 3 + 1];
    float z1 = xyz1[(b * N_ + n) * 3 + 2];
    float n1 = x1 * x1 + y1 * y1 + z1 * z1;
    float d1 = FLT_MAX, d2 = FLT_MAX, d3 = FLT_MAX;
    int   i1 = 0, i2 = 0, i3 = 0;
    for (int s = 0; s < S_; ++s) {
        float4 p = sp[s];
        float dot = x1 * p.x + y1 * p.y + z1 * p.z;
        float d = (n1 + p.w) - 2.0f * dot;     // matches reference expansion
        if (d < d3) {
            if (d < d2) {
                d3 = d2; i3 = i2;
                if (d < d1) { d2 = d1; i2 = i1; d1 = d; i1 = s; }
                else        { d2 = d;  i2 = s; }
            } else { d3 = d; i3 = s; }
        }
    }
    float r1 = 1.0f / (d1 + 1e-8f);
    float r2 = 1.0f / (d2 + 1e-8f);
    float r3 = 1.0f / (d3 + 1e-8f);
    float rs = 1.0f / (r1 + r2 + r3);
    size_t base = ((size_t)b * N_ + n) * 3;
    idx[base] = i1; idx[base + 1] = i2; idx[base + 2] = i3;
    wts[base] = r1 * rs; wts[base + 1] = r2 * rs; wts[base + 2] = r3 * rs;
}

// ---------- transpose points2 (B,C2,S) fp32 -> (B,S,C2) bf16 ----------
__global__ __launch_bounds__(256) void transpose_p2(
    const float* __restrict__ p2, unsigned short* __restrict__ p2t)
{
    __shared__ unsigned short tile[32][33];
    int b = blockIdx.z, s0 = blockIdx.x * 32, c0 = blockIdx.y * 32;
    #pragma unroll
    for (int j = 0; j < 4; ++j) {
        int c = threadIdx.y + j * 8;
        tile[c][threadIdx.x] = f2bf(p2[((size_t)b * C2_ + c0 + c) * S_ + s0 + threadIdx.x]);
    }
    __syncthreads();
    #pragma unroll
    for (int j = 0; j < 4; ++j) {
        int s = threadIdx.y + j * 8;
        p2t[((size_t)b * S_ + s0 + s) * C2_ + c0 + threadIdx.x] = tile[threadIdx.x][s];
    }
}

// ---------- build X1 (B,N,384) bf16, k-contiguous ----------
__global__ __launch_bounds__(256) void build_x1_kernel(
    const float* __restrict__ points1,            // (B,128,N) fp32
    const unsigned short* __restrict__ p2t,       // (B,S,256) bf16
    const int* __restrict__ idx, const float* __restrict__ wts,
    const float* __restrict__ te1,                // (B,384) f32
    unsigned short* __restrict__ X1)
{
    int b = blockIdx.y;
    int n = blockIdx.x * 256 + threadIdx.x;
    size_t base3 = ((size_t)b * N_ + n) * 3;
    int j0 = idx[base3], j1 = idx[base3 + 1], j2 = idx[base3 + 2];
    float w0 = wts[base3], w1 = wts[base3 + 1], w2 = wts[base3 + 2];
    unsigned short* xr = X1 + ((size_t)b * N_ + n) * CIN_;
    const float* te = te1 + b * CIN_;

    for (int c = 0; c < C1_; c += 8) {
        union { short8 v; unsigned short u[8]; } pk;
        #pragma unroll
        for (int jj = 0; jj < 8; ++jj) {
            float v = points1[((size_t)b * C1_ + c + jj) * N_ + n] + te[c + jj];
            pk.u[jj] = f2bf(v);
        }
        *(short8*)&xr[c] = pk.v;
    }
    const unsigned short* r0 = p2t + ((size_t)b * S_ + j0) * C2_;
    const unsigned short* r1 = p2t + ((size_t)b * S_ + j1) * C2_;
    const unsigned short* r2 = p2t + ((size_t)b * S_ + j2) * C2_;
    for (int c = 0; c < C2_; c += 8) {
        union { short8 v; unsigned short u[8]; } a0, a1, a2, pk;
        a0.v = *(const short8*)&r0[c];
        a1.v = *(const short8*)&r1[c];
        a2.v = *(const short8*)&r2[c];
        #pragma unroll
        for (int jj = 0; jj < 8; ++jj) {
            float v = w0 * bf2f(a0.u[jj]) + w1 * bf2f(a1.u[jj]) + w2 * bf2f(a2.u[jj])
                    + te[C1_ + c + jj];
            pk.u[jj] = f2bf(v);
        }
        *(short8*)&xr[C1_ + c] = pk.v;
    }
}

// ---------- GEMM (m97-style, B^T input) ----------
// A: (256, K) row-major bf16.  X: (B, 8192, K) k-contiguous bf16.
// MODE 0: out[b][n][o] bf16 (for next layer's B^T input)
// MODE 1: out[b][o][n] bf16 (final layout)
template <int K, int MODE>
__global__ __launch_bounds__(256) void gemm_bt(
    const unsigned short* __restrict__ A,
    const unsigned short* __restrict__ X,
    const float* __restrict__ bias,
    unsigned short* __restrict__ out)
{
    __shared__ unsigned short sA[128 * 64];
    __shared__ unsigned short sB[128 * 64];
    const int tid = threadIdx.x;
    const int lane = tid & 63, wave = tid >> 6;
    const int wo = wave >> 1, wm = wave & 1;
    const int quad = lane >> 4, col = lane & 15;
    const int b = blockIdx.z;
    const int o0 = blockIdx.y * 128;
    const int n0 = blockIdx.x * 128;
    const unsigned short* Xb = X + (size_t)b * N_ * K;

    f32x4 acc[4][4];
    #pragma unroll
    for (int i = 0; i < 4; ++i)
        #pragma unroll
        for (int j = 0; j < 4; ++j) acc[i][j] = (f32x4){0.f, 0.f, 0.f, 0.f};

    for (int k0 = 0; k0 < K; k0 += 64) {
        #pragma unroll
        for (int i = 0; i < 4; ++i) {
            int chunk = i * 256 + tid;
            int row = chunk >> 3, c8 = chunk & 7;
            async16(&A [(o0 + row) * K + k0 + c8 * 8], &sA[chunk * 8]);
            async16(&Xb[(size_t)(n0 + row) * K + k0 + c8 * 8], &sB[chunk * 8]);
        }
        __syncthreads();
        #pragma unroll
        for (int kk = 0; kk < 64; kk += 32) {
            short8 af[4], bfr[4];
            #pragma unroll
            for (int i = 0; i < 4; ++i)
                af[i] = *(const short8*)&sA[(wo * 64 + i * 16 + col) * 64 + kk + quad * 8];
            #pragma unroll
            for (int j = 0; j < 4; ++j)
                bfr[j] = *(const short8*)&sB[(wm * 64 + j * 16 + col) * 64 + kk + quad * 8];
            #pragma unroll
            for (int i = 0; i < 4; ++i)
                #pragma unroll
                for (int j = 0; j < 4; ++j)
                    acc[i][j] = __builtin_amdgcn_mfma_f32_16x16x32_bf16(af[i], bfr[j], acc[i][j], 0, 0, 0);
        }
        __syncthreads();
    }

    #pragma unroll
    for (int i = 0; i < 4; ++i) {
        int oo = o0 + wo * 64 + i * 16 + quad * 4;
        float bv0 = bias[oo + 0], bv1 = bias[oo + 1];
        float bv2 = bias[oo + 2], bv3 = bias[oo + 3];
        #pragma unroll
        for (int j = 0; j < 4; ++j) {
            int nn = n0 + wm * 64 + j * 16 + col;
            float v0 = acc[i][j][0] + bv0, v1 = acc[i][j][1] + bv1;
            float v2 = acc[i][j][2] + bv2, v3 = acc[i][j][3] + bv3;
            if (MODE == 0) {
                union { unsigned short u[4]; uint2 p; } pk;
                pk.u[0] = f2bf(v0); pk.u[1] = f2bf(v1);
                pk.u[2] = f2bf(v2); pk.u[3] = f2bf(v3);
                *(uint2*)&out[((size_t)b * N_ + nn) * CO_ + oo] = pk.p;
            } else {
                out[((size_t)b * CO_ + oo + 0) * N_ + nn] = f2bf(v0);
                out[((size_t)b * CO_ + oo + 1) * N_ + nn] = f2bf(v1);
                out[((size_t)b * CO_ + oo + 2) * N_ + nn] = f2bf(v2);
                out[((size_t)b * CO_ + oo + 3) * N_ + nn] = f2bf(v3);
            }
        }
    }
}

// ---------- stats over (n,o)-major bf16 buffer ----------
__global__ __launch_bounds__(256) void stats_rows_kernel(
    const unsigned short* __restrict__ y, float* __restrict__ sum, float* __restrict__ sq)
{
    int o = threadIdx.x;
    int r0 = blockIdx.x * 128;
    float s = 0.f, q = 0.f;
    for (int r = r0; r < r0 + 128; ++r) {
        float v = bf2f(y[(size_t)r * CO_ + o]);
        s += v; q += v * v;
    }
    atomicAdd(&sum[o], s);
    atomicAdd(&sq[o], q);
}

// ---------- stats over (o,n)-major bf16 buffer ----------
__global__ __launch_bounds__(256) void stats_cols_kernel(
    const unsigned short* __restrict__ z, float* __restrict__ sum, float* __restrict__ sq)
{
    __shared__ float ls[4], lq[4];
    int row = blockIdx.x;                 // (b*256 + o)
    int o = row & (CO_ - 1);
    const unsigned short* zr = z + (size_t)row * N_;
    float s = 0.f, q = 0.f;
    for (int i = threadIdx.x; i < N_; i += 256) {
        float v = bf2f(zr[i]); s += v; q += v * v;
    }
    for (int off = 32; off > 0; off >>= 1) { s += __shfl_down(s, off); q += __shfl_down(q, off); }
    int lane = threadIdx.x & 63, wave = threadIdx.x >> 6;
    if (lane == 0) { ls[wave] = s; lq[wave] = q; }
    __syncthreads();
    if (threadIdx.x == 0) {
        atomicAdd(&sum[o], ls[0] + ls[1] + ls[2] + ls[3]);
        atomicAdd(&sq[o],  lq[0] + lq[1] + lq[2] + lq[3]);
    }
}

// ---------- BN params (fp32 gamma/beta) ----------
__global__ void bnparam_kernel(const float* __restrict__ sum, const float* __restrict__ sq,
                               const float* __restrict__ gamma,
                               const float* __restrict__ beta,
                               float* __restrict__ scale, float* __restrict__ shift)
{
    int o = threadIdx.x;
    const float inv = 1.0f / 65536.0f;
    float m = sum[o] * inv;
    float var = fmaxf(sq[o] * inv - m * m, 0.f);
    float sc = gamma[o] / sqrtf(var + 1e-5f);
    scale[o] = sc;
    shift[o] = beta[o] - m * sc;
}

// ---------- in-place: x2 = gelu(scale*y + shift) + te2, layout (B,N,256) bf16 ----------
__global__ __launch_bounds__(256) void apply1_kernel(
    unsigned short* __restrict__ y, const float* __restrict__ scale,
    const float* __restrict__ shift, const float* __restrict__ te2)
{
    __shared__ float ssc[CO_], ssh[CO_], ste[CO_];
    int b = blockIdx.x >> 10;             // 1024 blocks per batch
    int t = threadIdx.x;
    ssc[t] = scale[t]; ssh[t] = shift[t]; ste[t] = te2[b * CO_ + t];
    __syncthreads();
    int g = blockIdx.x * 256 + t;
    int row = g >> 5;
    int og = (g & 31) * 8;
    unsigned short* p = y + (size_t)row * CO_ + og;
    union { short8 v; unsigned short u[8]; } in, op;
    in.v = *(short8*)p;
    #pragma unroll
    for (int jj = 0; jj < 8; ++jj) {
        int o = og + jj;
        op.u[jj] = f2bf(gelu_f(ssc[o] * bf2f(in.u[jj]) + ssh[o]) + ste[o]);
    }
    *(short8*)p = op.v;
}

// ---------- final: out = gelu(scale*z + shift), layout (B,256,N), fp32 out ----------
__global__ __launch_bounds__(256) void final_kernel(
    const unsigned short* __restrict__ z, const float* __restrict__ scale,
    const float* __restrict__ shift, float* __restrict__ out)
{
    int g = blockIdx.x * 256 + threadIdx.x;
    size_t e = (size_t)g * 8;
    int row = (int)(e >> 13);
    int o = row & (CO_ - 1);
    float sc = scale[o], sh = shift[o];
    union { short8 v; unsigned short u[8]; } in;
    in.v = *(const short8*)&z[e];
    float vo[8];
    #pragma unroll
    for (int jj = 0; jj < 8; ++jj)
        vo[jj] = gelu_f(sc * bf2f(in.u[jj]) + sh);
    *(float4*)&out[e]     = make_float4(vo[0], vo[1], vo[2], vo[3]);
    *(float4*)&out[e + 4] = make_float4(vo[4], vo[5], vo[6], vo[7]);
}

// ---------- launch ----------
extern "C" void kernel_launch(void* const* d_in, const int* in_sizes, int n_in,
                              void* d_out, int out_size, void* d_ws, size_t ws_size,
                              hipStream_t stream)
{
    (void)in_sizes; (void)n_in; (void)out_size; (void)ws_size;
    const float* xyz1    = (const float*)d_in[0];
    const float* xyz2    = (const float*)d_in[1];
    const float* points1 = (const float*)d_in[2];
    const float* points2 = (const float*)d_in[3];
    const float* t_embed = (const float*)d_in[4];
    const float* w_t1    = (const float*)d_in[5];
    const float* b_t1    = (const float*)d_in[6];
    const float* w_c1    = (const float*)d_in[7];
    const float* b_c1    = (const float*)d_in[8];
    const float* g1      = (const float*)d_in[9];
    const float* be1     = (const float*)d_in[10];
    const float* w_t2    = (const float*)d_in[11];
    const float* b_t2    = (const float*)d_in[12];
    const float* w_c2    = (const float*)d_in[13];
    const float* b_c2    = (const float*)d_in[14];
    const float* g2      = (const float*)d_in[15];
    const float* be2     = (const float*)d_in[16];

    char* w = (char*)d_ws;
    float* te1        = (float*)(w + OFF_TE1);
    float* te2        = (float*)(w + OFF_TE2);
    float* s1_sum     = (float*)(w + OFF_STATS);
    float* s1_sq      = s1_sum + 256;
    float* s2_sum     = s1_sum + 512;
    float* s2_sq      = s1_sum + 768;
    float* scale1     = (float*)(w + OFF_BN1);
    float* shift1     = scale1 + 256;
    float* scale2     = (float*)(w + OFF_BN2);
    float* shift2     = scale2 + 256;
    int*   idx        = (int*)(w + OFF_IDX);
    float* wts        = (float*)(w + OFF_WTS);
    unsigned short* wc1 = (unsigned short*)(w + OFF_WC1);
    unsigned short* wc2 = (unsigned short*)(w + OFF_WC2);
    unsigned short* p2t = (unsigned short*)(w + OFF_P2T);
    unsigned short* X1  = (unsigned short*)(w + OFF_X1);
    unsigned short* Z   = (unsigned short*)(w + OFF_X1);   // reuse X1 region after gemm1
    unsigned short* Y   = (unsigned short*)(w + OFF_Y);
    float* out = (float*)d_out;

    hipMemsetAsync(w + OFF_STATS, 0, 4096, stream);

    hipLaunchKernelGGL(wcvt_kernel, dim3(CIN_ * CO_ / 256), dim3(256), 0, stream,
                       w_c1, w_c2, wc1, wc2);
    hipLaunchKernelGGL(te_kernel, dim3(B_), dim3(640), 0, stream,
                       t_embed, w_t1, b_t1, w_t2, b_t2, te1, te2);
    hipLaunchKernelGGL(knn_kernel, dim3(N_ / 256, B_), dim3(256), 0, stream,
                       xyz1, xyz2, idx, wts);
    hipLaunchKernelGGL(transpose_p2, dim3(S_ / 32, C2_ / 32, B_), dim3(32, 8), 0, stream,
                       points2, p2t);
    hipLaunchKernelGGL(build_x1_kernel, dim3(N_ / 256, B_), dim3(256), 0, stream,
                       points1, p2t, idx, wts, te1, X1);
    hipLaunchKernelGGL((gemm_bt<CIN_, 0>), dim3(N_ / 128, CO_ / 128, B_), dim3(256), 0, stream,
                       wc1, X1, b_c1, Y);
    hipLaunchKernelGGL(stats_rows_kernel, dim3(512), dim3(256), 0, stream, Y, s1_sum, s1_sq);
    hipLaunchKernelGGL(bnparam_kernel, dim3(1), dim3(256), 0, stream,
                       s1_sum, s1_sq, g1, be1, scale1, shift1);
    hipLaunchKernelGGL(apply1_kernel, dim3(8192), dim3(256), 0, stream,
                       Y, scale1, shift1, te2);
    hipLaunchKernelGGL((gemm_bt<CO_, 1>), dim3(N_ / 128, CO_ / 128, B_), dim3(256), 0, stream,
                       wc2, Y, b_c2, Z);
    hipLaunchKernelGGL(stats_cols_kernel, dim3(B_ * CO_), dim3(256), 0, stream, Z, s2_sum, s2_sq);
    hipLaunchKernelGGL(bnparam_kernel, dim3(1), dim3(256), 0, stream,
                       s2_sum, s2_sq, g2, be2, scale2, shift2);
    hipLaunchKernelGGL(final_kernel, dim3(8192), dim3(256), 0, stream,
                       Z, scale2, shift2, out);
}